// Round 5
// baseline (339.229 us; speedup 1.0000x reference)
//
#include <hip/hip_runtime.h>

#define NB 4
#define NH 16
#define SS 2048
#define DD 64
#define QT 256     // query rows per block (32 per wave, 8 waves)
#define KT 64      // keys per tile (two 32-key halves)
#define NT (SS / KT)
#define KSP 72     // padded LDS row stride (bf16) -- measured conflict-free
#define QSCALE 0.18033688011112042f   // (1/8) * log2(e)  -> exp2 domain

#define WS_BITS_BYTES ((size_t)NB * SS * (SS / 8))   // 2 MiB
#define WS_KB_OFF  ((size_t)2  << 20)                // bf16 K (natural), 16 MiB
#define WS_VB_OFF  ((size_t)18 << 20)                // bf16 V fragments, 16 MiB
#define WS_FULL    ((size_t)34 << 20)

typedef __bf16 bf16x8 __attribute__((ext_vector_type(8)));
typedef __bf16 bf16x2 __attribute__((ext_vector_type(2)));
typedef float  floatx16 __attribute__((ext_vector_type(16)));
typedef unsigned long long u64t;

static_assert(sizeof(bf16x8) == 16, "bf16x8 must be 16B");

__device__ __forceinline__ int pack2(float a, float b) {
    bf16x2 v; v[0] = (__bf16)a; v[1] = (__bf16)b;
    return __builtin_bit_cast(int, v);
}

// permuted V column so QK C-regs feed PV B-fragment verbatim
__device__ __forceinline__ int vperm_col(int k) {
    return 16 * (k >> 4) + 8 * ((k >> 2) & 1) + (k & 3) + 4 * ((k >> 3) & 1);
}
__device__ __forceinline__ int vperm_inv(int c) {
    return 16 * ((c >> 4) & 3) + 8 * ((c >> 2) & 1) + 4 * ((c >> 3) & 1) + (c & 3);
}

// ---- fallback pre-pass: pack mask only ----
__global__ __launch_bounds__(256)
void pack_mask_kernel(const int* __restrict__ M, u64t* __restrict__ bits)
{
    const int w    = (blockIdx.x * 256 + threadIdx.x) >> 6;   // 0..16383
    const int lane = threadIdx.x & 63;
    #pragma unroll 4
    for (int i = 0; i < 16; ++i) {
        const int gw   = i * 16384 + w;
        const size_t row = (size_t)(gw >> 5);
        const int word = gw & 31;
        const int mval = M[row * SS + (size_t)word * 64 + lane];
        const u64t b = __ballot(mval == 1);
        if (lane == 0) bits[gw] = b;
    }
}

// ---- full pre-pass: K->bf16 (natural), V->bf16 PV-fragment stream, mask->bits ----
// blocks 0..2047: (bh,tt) K/V tile prep.  blocks 2048..6143: mask pack.
//
// VB fragment layout per (bh, tile): 8 chunks x 64 lanes x 8 bf16 (16B), chunk
// g = half*4 + s2*2 + a.  Lane l of chunk g holds, for j=0..7:
//   V_tile[ vperm_inv(32*half + 16*s2 + 8*(l>>5) + j) ][ 32*a + (l&31) ]
// i.e. exactly the av0/av1 operand the attn PV loop consumes.
__global__ __launch_bounds__(256)
void pre_kernel(const float* __restrict__ K, const float* __restrict__ V,
                const int* __restrict__ M, u64t* __restrict__ bits,
                __bf16* __restrict__ KB, __bf16* __restrict__ VB)
{
    __shared__ float vt[64][68];   // f32 V tile [key][dim], padded
    const int t = threadIdx.x;

    if (blockIdx.x < 2048) {
        const int bh = blockIdx.x >> 5;
        const int tt = blockIdx.x & 31;
        const size_t tb = (size_t)bh * SS * DD + (size_t)tt * (KT * DD);

        // K convert: pure elementwise, 16 elems/thread
        {
            const float* src = K + tb + t * 16;
            __bf16* dst = KB + tb + t * 16;
            float4 f0 = ((const float4*)src)[0];
            float4 f1 = ((const float4*)src)[1];
            float4 f2 = ((const float4*)src)[2];
            float4 f3 = ((const float4*)src)[3];
            bf16x8 o0, o1;
            o0[0]=(__bf16)f0.x; o0[1]=(__bf16)f0.y; o0[2]=(__bf16)f0.z; o0[3]=(__bf16)f0.w;
            o0[4]=(__bf16)f1.x; o0[5]=(__bf16)f1.y; o0[6]=(__bf16)f1.z; o0[7]=(__bf16)f1.w;
            o1[0]=(__bf16)f2.x; o1[1]=(__bf16)f2.y; o1[2]=(__bf16)f2.z; o1[3]=(__bf16)f2.w;
            o1[4]=(__bf16)f3.x; o1[5]=(__bf16)f3.y; o1[6]=(__bf16)f3.z; o1[7]=(__bf16)f3.w;
            ((bf16x8*)dst)[0] = o0;
            ((bf16x8*)dst)[1] = o1;
        }

        // V tile -> LDS (f32)
        {
            const int key = t >> 2, ds = (t & 3) * 16;
            const float* src = V + tb + (size_t)key * DD + ds;
            #pragma unroll
            for (int i = 0; i < 4; ++i)
                *(float4*)&vt[key][ds + 4 * i] = ((const float4*)src)[i];
        }
        __syncthreads();

        // V fragment stream out (512 slots of 16B; thread does slot t and t+256)
        {
            #pragma unroll
            for (int rep = 0; rep < 2; ++rep) {
                const int sIdx = t + 256 * rep;
                const int g = sIdx >> 6, l = sIdx & 63;
                const int half = g >> 2, s2 = (g >> 1) & 1, a = g & 1;
                const int colb = 32 * half + 16 * s2 + 8 * (l >> 5);
                const int dim  = 32 * a + (l & 31);
                bf16x8 o;
                #pragma unroll
                for (int j = 0; j < 8; ++j)
                    o[j] = (__bf16)vt[vperm_inv(colb + j)][dim];
                *(bf16x8*)(VB + tb + (size_t)sIdx * 8) = o;
            }
        }
    } else {
        const int w    = ((blockIdx.x - 2048) * 256 + t) >> 6;   // 0..16383
        const int lane = t & 63;
        #pragma unroll 4
        for (int i = 0; i < 16; ++i) {
            const int gw   = i * 16384 + w;
            const size_t row = (size_t)(gw >> 5);
            const int word = gw & 31;
            const int mval = M[row * SS + (size_t)word * 64 + lane];
            const u64t b = __ballot(mval == 1);
            if (lane == 0) bits[gw] = b;
        }
    }
}

// MODE 2: K in LDS (bf16 pre-converted), V fragments from global, raw barrier
// MODE 1: f32 staging for K+V in LDS + bit-mask (classic __syncthreads)
// MODE 0: f32 staging + raw int mask
template<int MODE>
__global__ __launch_bounds__(512, 4)
void attn_kernel(const float* __restrict__ Q, const float* __restrict__ K,
                 const float* __restrict__ V, const int* __restrict__ M,
                 const unsigned* __restrict__ MB,
                 const __bf16* __restrict__ KB, const __bf16* __restrict__ VB,
                 float* __restrict__ O)
{
    // K tiles double-buffered (padded, conflict-free measured).
    // vsT only used by MODE<=1 fallbacks.
    __shared__ __bf16 ks [2][KT][KSP];
    __shared__ __bf16 vsT[(MODE == 2) ? 1 : 2][DD][KSP];

    const int t    = threadIdx.x;
    const int wave = t >> 6;
    const int lane = t & 63;
    const int l31  = lane & 31;
    const int h8   = lane >> 5;

    // XCD-affinity decode: all 8 q-tiles of a head share blockIdx%8 -> one XCD L2
    const int bh    = blockIdx.x & 63;
    const int qtile = blockIdx.x >> 6;
    const int b     = bh >> 4;
    const int q0    = qtile * QT + wave * 32;

    const size_t base = (size_t)bh * SS * DD;

    // ---- persistent Q B-fragments: B[k=16s+8h8+j][n=q=l31], exp2 domain ----
    bf16x8 aq[4];
    {
        const float* qp = Q + base + (size_t)(q0 + l31) * DD + 8 * h8;
        #pragma unroll
        for (int s = 0; s < 4; ++s) {
            float4 f0 = *(const float4*)(qp + 16 * s);
            float4 f1 = *(const float4*)(qp + 16 * s + 4);
            bf16x8 a;
            a[0] = (__bf16)(f0.x * QSCALE); a[1] = (__bf16)(f0.y * QSCALE);
            a[2] = (__bf16)(f0.z * QSCALE); a[3] = (__bf16)(f0.w * QSCALE);
            a[4] = (__bf16)(f1.x * QSCALE); a[5] = (__bf16)(f1.y * QSCALE);
            a[6] = (__bf16)(f1.z * QSCALE); a[7] = (__bf16)(f1.w * QSCALE);
            aq[s] = a;
        }
    }

    // ones A-fragment for the denominator MFMA
    bf16x8 ones8;
    #pragma unroll
    for (int i = 0; i < 8; ++i) ones8[i] = (__bf16)1.0f;

    // ---- staging assignments ----
    const int srow = t >> 3;            // K key 0..63
    const int sc8  = (t & 7) * 8;
    const __bf16* kbp = KB + base + (size_t)srow * DD + sc8;
    bf16x8 kreg;

    // MODE2: per-lane V fragment stream pointer (16B/slot, 8 slots/tile)
    const __bf16* vfp = VB + base + (size_t)lane * 8;
    bf16x8 vfr[8];

    // MODE<=1: f32 staging
    const int skey = t >> 3;
    const int sdc  = (t & 7) * 8;
    const int vk   = 2 * (t & 31);
    const int vdc  = (t >> 5) * 4;
    const int vcol = vperm_col(vk);
    const float* kp0 = K + base + (size_t)skey * DD + sdc;
    const float* vp0 = V + base + (size_t)vk * DD + vdc;
    float4 ka0, ka1, va0, va1;

    // prologue: prefetch tile 0
    if constexpr (MODE == 2) {
        kreg = *(const bf16x8*)kbp;
    } else {
        ka0 = ((const float4*)kp0)[0];
        ka1 = ((const float4*)kp0)[1];
        va0 = *(const float4*)(vp0);
        va1 = *(const float4*)(vp0 + DD);
    }

    // mask pointers for row (q0 + l31); bits prefetched one tile ahead
    const u64t* mbrow = (const u64t*)MB + ((size_t)b * SS + q0 + l31) * (SS / 64);
    const int*  mrow  = M + (size_t)b * SS * SS + (size_t)(q0 + l31) * SS + 4 * h8;
    u64t mall = 0, mnext = 0;
    if constexpr (MODE >= 1) mall = mbrow[0];

    floatx16 o0, o1, oL;
    #pragma unroll
    for (int i = 0; i < 16; ++i) { o0[i] = 0.f; o1[i] = 0.f; oL[i] = 0.f; }

    for (int tt = 0; tt < NT; ++tt) {
        const int cur = tt & 1;

        // ---- stage K tile tt -> LDS buf[cur]; issue V fragment loads ----
        if constexpr (MODE == 2) {
            *(bf16x8*)&ks[cur][srow][sc8] = kreg;
            const __bf16* vt0 = vfp + (size_t)tt * (8 * 512);
            #pragma unroll
            for (int g = 0; g < 8; ++g)
                vfr[g] = *(const bf16x8*)(vt0 + g * 512);
        } else {
            bf16x8 kw;
            kw[0]=(__bf16)ka0.x; kw[1]=(__bf16)ka0.y; kw[2]=(__bf16)ka0.z; kw[3]=(__bf16)ka0.w;
            kw[4]=(__bf16)ka1.x; kw[5]=(__bf16)ka1.y; kw[6]=(__bf16)ka1.z; kw[7]=(__bf16)ka1.w;
            *(bf16x8*)&ks[cur][skey][sdc] = kw;
            #pragma unroll
            for (int i = 0; i < 4; ++i) {
                bf16x2 pr;
                pr[0] = (__bf16)(&va0.x)[i]; pr[1] = (__bf16)(&va1.x)[i];
                *(bf16x2*)&vsT[cur][vdc + i][vcol] = pr;
            }
        }

        // ---- barrier: MODE2 drains LDS only (VMEM stays in flight) ----
        if constexpr (MODE == 2) {
            asm volatile("s_waitcnt lgkmcnt(0)" ::: "memory");
            __builtin_amdgcn_s_barrier();
            asm volatile("" ::: "memory");
        } else {
            __syncthreads();
        }

        // ---- raw-mask fetch (MODE0 only) ----
        int4 mi[8];
        if constexpr (MODE == 0) {
            #pragma unroll
            for (int g = 0; g < 8; ++g)
                mi[g] = *(const int4*)(mrow + tt * KT + 8 * g);
        }

        // ---- prefetch next K tile (consumed by staging before next barrier) ----
        if constexpr (MODE == 2) {
            const size_t jn = (size_t)((tt + 1) & (NT - 1)) * (KT * DD);
            kreg = *(const bf16x8*)(kbp + jn);
        } else {
            const int jn = ((tt + 1) * KT) & (SS - 1);
            const float* kn = kp0 + (size_t)jn * DD;
            ka0 = ((const float4*)kn)[0];
            ka1 = ((const float4*)kn)[1];
            const float* vn = vp0 + (size_t)jn * DD;
            va0 = *(const float4*)(vn);
            va1 = *(const float4*)(vn + DD);
        }
        if constexpr (MODE >= 1) mnext = mbrow[(tt + 1) & (NT - 1)];

        // ---- compute: two 32-key halves ----
        #pragma unroll
        for (int half = 0; half < 2; ++half) {
            // mask-as-C-init: c[i] = masked ? -1024 : 0. After QK accumulation
            // masked scores are <= -1016, so exp2 flushes them to exactly 0.
            floatx16 c;
            if constexpr (MODE >= 1) {
                const unsigned u = (unsigned)(mall >> (32 * half)) >> (4 * h8);
                #pragma unroll
                for (int i = 0; i < 16; ++i) {
                    const int pos = (i & 3) + 8 * (i >> 2);
                    const int sm = ((int)(u << (31 - pos))) >> 31;   // -1 if masked
                    c[i] = __builtin_bit_cast(float, sm & (int)0xC4800000u); // -1024.0f
                }
            } else {
                #pragma unroll
                for (int i = 0; i < 16; ++i) {
                    const int g2 = 4 * half + (i >> 2);
                    c[i] = ((&mi[g2].x)[i & 3] == 1) ? -1024.0f : 0.0f;
                }
            }

            // S^T = K·Q^T : C[m=key][n=q=l31], key=(i&3)+8(i>>2)+4h8 (+32*half)
            __builtin_amdgcn_s_setprio(1);
            #pragma unroll
            for (int s = 0; s < 4; ++s) {
                bf16x8 a = *(const bf16x8*)&ks[cur][32 * half + l31][16 * s + 8 * h8];
                c = __builtin_amdgcn_mfma_f32_32x32x16_bf16(a, aq[s], c, 0, 0, 0);
            }
            __builtin_amdgcn_s_setprio(0);

            // p = exp2(c) -> packed bf16 pairs (masked lanes already 0)
            int pk[8];
            #pragma unroll
            for (int g = 0; g < 8; ++g) {
                float pa = __builtin_amdgcn_exp2f(c[2 * g]);
                float pb = __builtin_amdgcn_exp2f(c[2 * g + 1]);
                pk[g] = pack2(pa, pb);
            }

            // PV: O^T += V^T(perm) · P^T ; oL += ones · P^T  (denominator)
            __builtin_amdgcn_s_setprio(1);
            #pragma unroll
            for (int s2 = 0; s2 < 2; ++s2) {
                int4 fw; fw.x = pk[4*s2]; fw.y = pk[4*s2+1]; fw.z = pk[4*s2+2]; fw.w = pk[4*s2+3];
                bf16x8 bp = __builtin_bit_cast(bf16x8, fw);
                bf16x8 av0, av1;
                if constexpr (MODE == 2) {
                    av0 = vfr[half * 4 + s2 * 2 + 0];
                    av1 = vfr[half * 4 + s2 * 2 + 1];
                } else {
                    av0 = *(const bf16x8*)&vsT[cur][l31]     [32 * half + 16 * s2 + 8 * h8];
                    av1 = *(const bf16x8*)&vsT[cur][32 + l31][32 * half + 16 * s2 + 8 * h8];
                }
                o0 = __builtin_amdgcn_mfma_f32_32x32x16_bf16(av0, bp, o0, 0, 0, 0);
                o1 = __builtin_amdgcn_mfma_f32_32x32x16_bf16(av1, bp, o1, 0, 0, 0);
                oL = __builtin_amdgcn_mfma_f32_32x32x16_bf16(ones8, bp, oL, 0, 0, 0);
            }
            __builtin_amdgcn_s_setprio(0);
        }

        if constexpr (MODE >= 1) mall = mnext;
    }

    // ---- epilogue: every oL reg holds sum_k p[k][col=l31] already ----
    float inv = 1.0f / oL[0];
    float* op = O + base + (size_t)(q0 + l31) * DD;
    #pragma unroll
    for (int s = 0; s < 4; ++s) {
        float4 st0, st1;
        st0.x = o0[4*s+0] * inv; st0.y = o0[4*s+1] * inv;
        st0.z = o0[4*s+2] * inv; st0.w = o0[4*s+3] * inv;
        st1.x = o1[4*s+0] * inv; st1.y = o1[4*s+1] * inv;
        st1.z = o1[4*s+2] * inv; st1.w = o1[4*s+3] * inv;
        *(float4*)(op + 8 * s + 4 * h8)      = st0;
        *(float4*)(op + 32 + 8 * s + 4 * h8) = st1;
    }
}

extern "C" void kernel_launch(void* const* d_in, const int* in_sizes, int n_in,
                              void* d_out, int out_size, void* d_ws, size_t ws_size,
                              hipStream_t stream) {
    (void)in_sizes; (void)n_in; (void)out_size;
    const float* q = (const float*)d_in[0];
    const float* k = (const float*)d_in[1];
    const float* v = (const float*)d_in[2];
    const int*   m = (const int*)d_in[3];
    float* out = (float*)d_out;
    dim3 grid(NB * NH * (SS / QT));   // 512 blocks = 2 per CU

    if (ws_size >= WS_FULL) {
        u64t*   bits = (u64t*)d_ws;
        __bf16* kb16 = (__bf16*)((char*)d_ws + WS_KB_OFF);
        __bf16* vb16 = (__bf16*)((char*)d_ws + WS_VB_OFF);
        pre_kernel<<<dim3(6144), 256, 0, stream>>>(k, v, m, bits, kb16, vb16);
        attn_kernel<2><<<grid, 512, 0, stream>>>(q, k, v, m, (const unsigned*)bits,
                                                 kb16, vb16, out);
    } else if (ws_size >= WS_BITS_BYTES) {
        u64t* bits = (u64t*)d_ws;
        pack_mask_kernel<<<dim3(4096), 256, 0, stream>>>(m, bits);
        attn_kernel<1><<<grid, 512, 0, stream>>>(q, k, v, m, (const unsigned*)bits,
                                                 nullptr, nullptr, out);
    } else {
        attn_kernel<0><<<grid, 512, 0, stream>>>(q, k, v, m, nullptr,
                                                 nullptr, nullptr, out);
    }
}

// Round 6
// 271.363 us; speedup vs baseline: 1.2501x; 1.2501x over previous
//
#include <hip/hip_runtime.h>

#define NB 4
#define NH 16
#define SS 2048
#define DD 64
#define QT 256     // query rows per block
#define KT 64      // keys per tile (two 32-key halves)
#define NT (SS / KT)
#define KSP 72     // padded LDS row stride (bf16) -- measured conflict-free
#define QSCALE 0.18033688011112042f   // (1/8) * log2(e)  -> exp2 domain

#define WS_BITS_BYTES ((size_t)NB * SS * (SS / 8))   // 2 MiB
#define WS_KB_OFF  ((size_t)2  << 20)                // bf16 K (natural), 16 MiB
#define WS_VB_OFF  ((size_t)18 << 20)                // bf16 V^T(perm) tiles, 16 MiB
#define WS_FULL    ((size_t)34 << 20)

typedef __bf16 bf16x8 __attribute__((ext_vector_type(8)));
typedef __bf16 bf16x2 __attribute__((ext_vector_type(2)));
typedef float  floatx16 __attribute__((ext_vector_type(16)));
typedef unsigned long long u64t;

static_assert(sizeof(bf16x8) == 16, "bf16x8 must be 16B");

__device__ __forceinline__ int pack2(float a, float b) {
    bf16x2 v; v[0] = (__bf16)a; v[1] = (__bf16)b;
    return __builtin_bit_cast(int, v);
}

// permuted V column so QK C-regs feed PV B-fragment verbatim
__device__ __forceinline__ int vperm_col(int k) {
    return 16 * (k >> 4) + 8 * ((k >> 2) & 1) + (k & 3) + 4 * ((k >> 3) & 1);
}
__device__ __forceinline__ int vperm_inv(int c) {
    return 16 * ((c >> 4) & 3) + 8 * ((c >> 2) & 1) + 4 * ((c >> 3) & 1) + (c & 3);
}

// ---- fallback pre-pass: pack mask only ----
__global__ __launch_bounds__(256)
void pack_mask_kernel(const int* __restrict__ M, u64t* __restrict__ bits)
{
    const int w    = (blockIdx.x * 256 + threadIdx.x) >> 6;   // 0..16383
    const int lane = threadIdx.x & 63;
    #pragma unroll 4
    for (int i = 0; i < 16; ++i) {
        const int gw   = i * 16384 + w;
        const size_t row = (size_t)(gw >> 5);
        const int word = gw & 31;
        const int mval = M[row * SS + (size_t)word * 64 + lane];
        const u64t b = __ballot(mval == 1);
        if (lane == 0) bits[gw] = b;
    }
}

// ---- full pre-pass: K->bf16 (natural), V->bf16 transposed+permuted tiles,
// mask->bits.  blocks 0..2047: (bh,tt) K/V tiles.  2048..6143: mask pack. ----
__global__ __launch_bounds__(256)
void pre_kernel(const float* __restrict__ K, const float* __restrict__ V,
                const int* __restrict__ M, u64t* __restrict__ bits,
                __bf16* __restrict__ KB, __bf16* __restrict__ VB)
{
    __shared__ float vt[64][68];   // f32 V tile [key][dim], padded
    const int t = threadIdx.x;

    if (blockIdx.x < 2048) {
        const int bh = blockIdx.x >> 5;
        const int tt = blockIdx.x & 31;
        const size_t tb = (size_t)bh * SS * DD + (size_t)tt * (KT * DD);

        // K convert: pure elementwise, 16 elems/thread
        {
            const float* src = K + tb + t * 16;
            __bf16* dst = KB + tb + t * 16;
            float4 f0 = ((const float4*)src)[0];
            float4 f1 = ((const float4*)src)[1];
            float4 f2 = ((const float4*)src)[2];
            float4 f3 = ((const float4*)src)[3];
            bf16x8 o0, o1;
            o0[0]=(__bf16)f0.x; o0[1]=(__bf16)f0.y; o0[2]=(__bf16)f0.z; o0[3]=(__bf16)f0.w;
            o0[4]=(__bf16)f1.x; o0[5]=(__bf16)f1.y; o0[6]=(__bf16)f1.z; o0[7]=(__bf16)f1.w;
            o1[0]=(__bf16)f2.x; o1[1]=(__bf16)f2.y; o1[2]=(__bf16)f2.z; o1[3]=(__bf16)f2.w;
            o1[4]=(__bf16)f3.x; o1[5]=(__bf16)f3.y; o1[6]=(__bf16)f3.z; o1[7]=(__bf16)f3.w;
            ((bf16x8*)dst)[0] = o0;
            ((bf16x8*)dst)[1] = o1;
        }

        // V tile -> LDS (f32), then transposed+permuted bf16 out [dim][64]
        {
            const int key = t >> 2, ds = (t & 3) * 16;
            const float* src = V + tb + (size_t)key * DD + ds;
            #pragma unroll
            for (int i = 0; i < 4; ++i)
                *(float4*)&vt[key][ds + 4 * i] = ((const float4*)src)[i];
        }
        __syncthreads();
        {
            const int dim = t >> 2, cb = (t & 3) * 16;
            bf16x8 o0, o1;
            #pragma unroll
            for (int c = 0; c < 16; ++c) {
                const float vvv = vt[vperm_inv(cb + c)][dim];
                if (c < 8) o0[c] = (__bf16)vvv; else o1[c - 8] = (__bf16)vvv;
            }
            __bf16* dst = VB + tb + (size_t)dim * 64 + cb;
            ((bf16x8*)dst)[0] = o0;
            ((bf16x8*)dst)[1] = o1;
        }
    } else {
        const int w    = ((blockIdx.x - 2048) * 256 + t) >> 6;   // 0..16383
        const int lane = t & 63;
        #pragma unroll 4
        for (int i = 0; i < 16; ++i) {
            const int gw   = i * 16384 + w;
            const size_t row = (size_t)(gw >> 5);
            const int word = gw & 31;
            const int mval = M[row * SS + (size_t)word * 64 + lane];
            const u64t b = __ballot(mval == 1);
            if (lane == 0) bits[gw] = b;
        }
    }
}

// ===================== fast path: 4 waves, 64 q-rows per wave ================
// Each K/V LDS fragment read feeds TWO q-column groups -> per-CU LDS traffic
// nearly halves vs the 8-wave/32-q layout (which was the max-loaded pipe).
__global__ __launch_bounds__(256, 2)
void attn2_kernel(const float* __restrict__ Q, const unsigned* __restrict__ MBu,
                  const __bf16* __restrict__ KB, const __bf16* __restrict__ VB,
                  float* __restrict__ O)
{
    __shared__ __bf16 ks [2][KT][KSP];   // [buf][key][dim]
    __shared__ __bf16 vsT[2][DD][KSP];   // [buf][dim][perm-key]

    const int t    = threadIdx.x;
    const int wave = t >> 6;
    const int lane = t & 63;
    const int l31  = lane & 31;
    const int h8   = lane >> 5;

    // XCD-affinity decode: all 8 q-tiles of a head share blockIdx%8 -> one XCD L2
    const int bh    = blockIdx.x & 63;
    const int qtile = blockIdx.x >> 6;          // 0..7
    const int b     = bh >> 4;
    const int q0    = qtile * QT + wave * 64;   // 64 q-rows per wave

    const size_t base = (size_t)bh * SS * DD;

    // ---- persistent Q B-fragments for the two 32-q groups ----
    bf16x8 aqA[4], aqB[4];
    #pragma unroll
    for (int grp = 0; grp < 2; ++grp) {
        const float* qp = Q + base + (size_t)(q0 + 32 * grp + l31) * DD + 8 * h8;
        #pragma unroll
        for (int s = 0; s < 4; ++s) {
            float4 f0 = *(const float4*)(qp + 16 * s);
            float4 f1 = *(const float4*)(qp + 16 * s + 4);
            bf16x8 a;
            a[0] = (__bf16)(f0.x * QSCALE); a[1] = (__bf16)(f0.y * QSCALE);
            a[2] = (__bf16)(f0.z * QSCALE); a[3] = (__bf16)(f0.w * QSCALE);
            a[4] = (__bf16)(f1.x * QSCALE); a[5] = (__bf16)(f1.y * QSCALE);
            a[6] = (__bf16)(f1.z * QSCALE); a[7] = (__bf16)(f1.w * QSCALE);
            if (grp == 0) aqA[s] = a; else aqB[s] = a;
        }
    }

    bf16x8 ones8;
    #pragma unroll
    for (int i = 0; i < 8; ++i) ones8[i] = (__bf16)1.0f;

    // ---- staging: thread stages rows srow and srow+32 of K and of V^T ----
    const int srow = t >> 3;            // 0..31
    const int sc8  = (t & 7) * 8;
    const __bf16* kbp = KB + base + (size_t)srow * DD + sc8;
    const __bf16* vbp = VB + base + (size_t)srow * DD + sc8;
    bf16x8 kr0, kr1, vr0, vr1;

    kr0 = *(const bf16x8*)kbp;
    kr1 = *(const bf16x8*)(kbp + 32 * DD);
    vr0 = *(const bf16x8*)vbp;
    vr1 = *(const bf16x8*)(vbp + 32 * DD);

    // mask rows for the two q groups, prefetched one tile ahead
    const u64t* mbrA = (const u64t*)MBu + ((size_t)b * SS + q0 + l31)      * (SS / 64);
    const u64t* mbrB = (const u64t*)MBu + ((size_t)b * SS + q0 + 32 + l31) * (SS / 64);
    u64t mA = mbrA[0], mB = mbrB[0], mnA, mnB;

    floatx16 o0A, o1A, oLA, o0B, o1B, oLB;
    #pragma unroll
    for (int i = 0; i < 16; ++i) {
        o0A[i] = 0.f; o1A[i] = 0.f; oLA[i] = 0.f;
        o0B[i] = 0.f; o1B[i] = 0.f; oLB[i] = 0.f;
    }

    for (int tt = 0; tt < NT; ++tt) {
        const int cur = tt & 1;

        // ---- stage K/V tile tt -> LDS buf[cur] ----
        *(bf16x8*)&ks [cur][srow]     [sc8] = kr0;
        *(bf16x8*)&ks [cur][srow + 32][sc8] = kr1;
        *(bf16x8*)&vsT[cur][srow]     [sc8] = vr0;
        *(bf16x8*)&vsT[cur][srow + 32][sc8] = vr1;

        // barrier draining LDS only; VMEM prefetches stay in flight
        asm volatile("s_waitcnt lgkmcnt(0)" ::: "memory");
        __builtin_amdgcn_s_barrier();
        asm volatile("" ::: "memory");

        // ---- prefetch next tile + next mask words ----
        {
            const size_t jn = (size_t)((tt + 1) & (NT - 1)) * (KT * DD);
            kr0 = *(const bf16x8*)(kbp + jn);
            kr1 = *(const bf16x8*)(kbp + jn + 32 * DD);
            vr0 = *(const bf16x8*)(vbp + jn);
            vr1 = *(const bf16x8*)(vbp + jn + 32 * DD);
        }
        mnA = mbrA[(tt + 1) & (NT - 1)];
        mnB = mbrB[(tt + 1) & (NT - 1)];

        // ---- compute: two 32-key halves x two q-groups ----
        #pragma unroll
        for (int half = 0; half < 2; ++half) {
            // mask-as-C-init: c[i] = masked ? -1024 : 0 (exp2 flushes to 0)
            floatx16 cA, cB;
            {
                const unsigned uA = (unsigned)(mA >> (32 * half)) >> (4 * h8);
                const unsigned uB = (unsigned)(mB >> (32 * half)) >> (4 * h8);
                #pragma unroll
                for (int i = 0; i < 16; ++i) {
                    const int pos = (i & 3) + 8 * (i >> 2);
                    const int sA = ((int)(uA << (31 - pos))) >> 31;
                    const int sB = ((int)(uB << (31 - pos))) >> 31;
                    cA[i] = __builtin_bit_cast(float, sA & (int)0xC4800000u);
                    cB[i] = __builtin_bit_cast(float, sB & (int)0xC4800000u);
                }
            }

            // S^T = K·Q^T for both groups; each K fragment read used twice
            __builtin_amdgcn_s_setprio(1);
            #pragma unroll
            for (int s = 0; s < 4; ++s) {
                bf16x8 a = *(const bf16x8*)&ks[cur][32 * half + l31][16 * s + 8 * h8];
                cA = __builtin_amdgcn_mfma_f32_32x32x16_bf16(a, aqA[s], cA, 0, 0, 0);
                cB = __builtin_amdgcn_mfma_f32_32x32x16_bf16(a, aqB[s], cB, 0, 0, 0);
            }
            __builtin_amdgcn_s_setprio(0);

            // p = exp2(c) -> packed bf16 pairs (masked already 0)
            int pkA[8], pkB[8];
            #pragma unroll
            for (int g = 0; g < 8; ++g) {
                float a0 = __builtin_amdgcn_exp2f(cA[2 * g]);
                float a1 = __builtin_amdgcn_exp2f(cA[2 * g + 1]);
                float b0 = __builtin_amdgcn_exp2f(cB[2 * g]);
                float b1 = __builtin_amdgcn_exp2f(cB[2 * g + 1]);
                pkA[g] = pack2(a0, a1);
                pkB[g] = pack2(b0, b1);
            }

            // PV + denominator; each V fragment read used twice
            __builtin_amdgcn_s_setprio(1);
            #pragma unroll
            for (int s2 = 0; s2 < 2; ++s2) {
                bf16x8 av0 = *(const bf16x8*)&vsT[cur][l31]     [32 * half + 16 * s2 + 8 * h8];
                bf16x8 av1 = *(const bf16x8*)&vsT[cur][32 + l31][32 * half + 16 * s2 + 8 * h8];
                int4 fwA; fwA.x = pkA[4*s2]; fwA.y = pkA[4*s2+1]; fwA.z = pkA[4*s2+2]; fwA.w = pkA[4*s2+3];
                int4 fwB; fwB.x = pkB[4*s2]; fwB.y = pkB[4*s2+1]; fwB.z = pkB[4*s2+2]; fwB.w = pkB[4*s2+3];
                bf16x8 bpA = __builtin_bit_cast(bf16x8, fwA);
                bf16x8 bpB = __builtin_bit_cast(bf16x8, fwB);
                o0A = __builtin_amdgcn_mfma_f32_32x32x16_bf16(av0, bpA, o0A, 0, 0, 0);
                o0B = __builtin_amdgcn_mfma_f32_32x32x16_bf16(av0, bpB, o0B, 0, 0, 0);
                o1A = __builtin_amdgcn_mfma_f32_32x32x16_bf16(av1, bpA, o1A, 0, 0, 0);
                o1B = __builtin_amdgcn_mfma_f32_32x32x16_bf16(av1, bpB, o1B, 0, 0, 0);
                oLA = __builtin_amdgcn_mfma_f32_32x32x16_bf16(ones8, bpA, oLA, 0, 0, 0);
                oLB = __builtin_amdgcn_mfma_f32_32x32x16_bf16(ones8, bpB, oLB, 0, 0, 0);
            }
            __builtin_amdgcn_s_setprio(0);
        }

        mA = mnA; mB = mnB;
    }

    // ---- epilogue: every oL* reg holds the full denominator for q-col l31 ----
    const float invA = 1.0f / oLA[0];
    const float invB = 1.0f / oLB[0];
    float* opA = O + base + (size_t)(q0 + l31) * DD;
    float* opB = O + base + (size_t)(q0 + 32 + l31) * DD;
    #pragma unroll
    for (int s = 0; s < 4; ++s) {
        float4 st;
        st.x = o0A[4*s+0] * invA; st.y = o0A[4*s+1] * invA;
        st.z = o0A[4*s+2] * invA; st.w = o0A[4*s+3] * invA;
        *(float4*)(opA + 8 * s + 4 * h8) = st;
        st.x = o1A[4*s+0] * invA; st.y = o1A[4*s+1] * invA;
        st.z = o1A[4*s+2] * invA; st.w = o1A[4*s+3] * invA;
        *(float4*)(opA + 32 + 8 * s + 4 * h8) = st;
        st.x = o0B[4*s+0] * invB; st.y = o0B[4*s+1] * invB;
        st.z = o0B[4*s+2] * invB; st.w = o0B[4*s+3] * invB;
        *(float4*)(opB + 8 * s + 4 * h8) = st;
        st.x = o1B[4*s+0] * invB; st.y = o1B[4*s+1] * invB;
        st.z = o1B[4*s+2] * invB; st.w = o1B[4*s+3] * invB;
        *(float4*)(opB + 32 + 8 * s + 4 * h8) = st;
    }
}

// ===================== fallback path (R4-verified): 8 waves, 32 q per wave ===
// MODE 1: f32 staging + bit-mask.  MODE 0: f32 staging + raw int mask.
template<int MODE>
__global__ __launch_bounds__(512, 4)
void attn_kernel(const float* __restrict__ Q, const float* __restrict__ K,
                 const float* __restrict__ V, const int* __restrict__ M,
                 const unsigned* __restrict__ MB, float* __restrict__ O)
{
    __shared__ __bf16 ks [2][KT][KSP];
    __shared__ __bf16 vsT[2][DD][KSP];

    const int t    = threadIdx.x;
    const int wave = t >> 6;
    const int lane = t & 63;
    const int l31  = lane & 31;
    const int h8   = lane >> 5;

    const int bh    = blockIdx.x & 63;
    const int qtile = blockIdx.x >> 6;
    const int b     = bh >> 4;
    const int q0    = qtile * QT + wave * 32;

    const size_t base = (size_t)bh * SS * DD;

    bf16x8 aq[4];
    {
        const float* qp = Q + base + (size_t)(q0 + l31) * DD + 8 * h8;
        #pragma unroll
        for (int s = 0; s < 4; ++s) {
            float4 f0 = *(const float4*)(qp + 16 * s);
            float4 f1 = *(const float4*)(qp + 16 * s + 4);
            bf16x8 a;
            a[0] = (__bf16)(f0.x * QSCALE); a[1] = (__bf16)(f0.y * QSCALE);
            a[2] = (__bf16)(f0.z * QSCALE); a[3] = (__bf16)(f0.w * QSCALE);
            a[4] = (__bf16)(f1.x * QSCALE); a[5] = (__bf16)(f1.y * QSCALE);
            a[6] = (__bf16)(f1.z * QSCALE); a[7] = (__bf16)(f1.w * QSCALE);
            aq[s] = a;
        }
    }

    bf16x8 ones8;
    #pragma unroll
    for (int i = 0; i < 8; ++i) ones8[i] = (__bf16)1.0f;

    const int skey = t >> 3;
    const int sdc  = (t & 7) * 8;
    const int vk   = 2 * (t & 31);
    const int vdc  = (t >> 5) * 4;
    const int vcol = vperm_col(vk);
    const float* kp0 = K + base + (size_t)skey * DD + sdc;
    const float* vp0 = V + base + (size_t)vk * DD + vdc;

    float4 ka0 = ((const float4*)kp0)[0];
    float4 ka1 = ((const float4*)kp0)[1];
    float4 va0 = *(const float4*)(vp0);
    float4 va1 = *(const float4*)(vp0 + DD);

    const u64t* mbrow = (const u64t*)MB + ((size_t)b * SS + q0 + l31) * (SS / 64);
    const int*  mrow  = M + (size_t)b * SS * SS + (size_t)(q0 + l31) * SS + 4 * h8;
    u64t mall = 0, mnext = 0;
    if constexpr (MODE >= 1) mall = mbrow[0];

    floatx16 o0, o1, oL;
    #pragma unroll
    for (int i = 0; i < 16; ++i) { o0[i] = 0.f; o1[i] = 0.f; oL[i] = 0.f; }

    for (int tt = 0; tt < NT; ++tt) {
        const int cur = tt & 1;

        {
            bf16x8 kw;
            kw[0]=(__bf16)ka0.x; kw[1]=(__bf16)ka0.y; kw[2]=(__bf16)ka0.z; kw[3]=(__bf16)ka0.w;
            kw[4]=(__bf16)ka1.x; kw[5]=(__bf16)ka1.y; kw[6]=(__bf16)ka1.z; kw[7]=(__bf16)ka1.w;
            *(bf16x8*)&ks[cur][skey][sdc] = kw;
            #pragma unroll
            for (int i = 0; i < 4; ++i) {
                bf16x2 pr;
                pr[0] = (__bf16)(&va0.x)[i]; pr[1] = (__bf16)(&va1.x)[i];
                *(bf16x2*)&vsT[cur][vdc + i][vcol] = pr;
            }
        }
        __syncthreads();

        int4 mi[8];
        if constexpr (MODE == 0) {
            #pragma unroll
            for (int g = 0; g < 8; ++g)
                mi[g] = *(const int4*)(mrow + tt * KT + 8 * g);
        }

        {
            const int jn = ((tt + 1) * KT) & (SS - 1);
            const float* kn = kp0 + (size_t)jn * DD;
            ka0 = ((const float4*)kn)[0];
            ka1 = ((const float4*)kn)[1];
            const float* vn = vp0 + (size_t)jn * DD;
            va0 = *(const float4*)(vn);
            va1 = *(const float4*)(vn + DD);
        }
        if constexpr (MODE >= 1) mnext = mbrow[(tt + 1) & (NT - 1)];

        #pragma unroll
        for (int half = 0; half < 2; ++half) {
            floatx16 c;
            if constexpr (MODE >= 1) {
                const unsigned u = (unsigned)(mall >> (32 * half)) >> (4 * h8);
                #pragma unroll
                for (int i = 0; i < 16; ++i) {
                    const int pos = (i & 3) + 8 * (i >> 2);
                    const int sm = ((int)(u << (31 - pos))) >> 31;
                    c[i] = __builtin_bit_cast(float, sm & (int)0xC4800000u);
                }
            } else {
                #pragma unroll
                for (int i = 0; i < 16; ++i) {
                    const int g2 = 4 * half + (i >> 2);
                    c[i] = ((&mi[g2].x)[i & 3] == 1) ? -1024.0f : 0.0f;
                }
            }

            __builtin_amdgcn_s_setprio(1);
            #pragma unroll
            for (int s = 0; s < 4; ++s) {
                bf16x8 a = *(const bf16x8*)&ks[cur][32 * half + l31][16 * s + 8 * h8];
                c = __builtin_amdgcn_mfma_f32_32x32x16_bf16(a, aq[s], c, 0, 0, 0);
            }
            __builtin_amdgcn_s_setprio(0);

            int pk[8];
            #pragma unroll
            for (int g = 0; g < 8; ++g) {
                float pa = __builtin_amdgcn_exp2f(c[2 * g]);
                float pb = __builtin_amdgcn_exp2f(c[2 * g + 1]);
                pk[g] = pack2(pa, pb);
            }

            __builtin_amdgcn_s_setprio(1);
            #pragma unroll
            for (int s2 = 0; s2 < 2; ++s2) {
                int4 fw; fw.x = pk[4*s2]; fw.y = pk[4*s2+1]; fw.z = pk[4*s2+2]; fw.w = pk[4*s2+3];
                bf16x8 bp = __builtin_bit_cast(bf16x8, fw);
                bf16x8 av0 = *(const bf16x8*)&vsT[cur][l31]     [32 * half + 16 * s2 + 8 * h8];
                bf16x8 av1 = *(const bf16x8*)&vsT[cur][32 + l31][32 * half + 16 * s2 + 8 * h8];
                o0 = __builtin_amdgcn_mfma_f32_32x32x16_bf16(av0, bp, o0, 0, 0, 0);
                o1 = __builtin_amdgcn_mfma_f32_32x32x16_bf16(av1, bp, o1, 0, 0, 0);
                oL = __builtin_amdgcn_mfma_f32_32x32x16_bf16(ones8, bp, oL, 0, 0, 0);
            }
            __builtin_amdgcn_s_setprio(0);
        }

        if constexpr (MODE >= 1) mall = mnext;
    }

    float inv = 1.0f / oL[0];
    float* op = O + base + (size_t)(q0 + l31) * DD;
    #pragma unroll
    for (int s = 0; s < 4; ++s) {
        float4 st0, st1;
        st0.x = o0[4*s+0] * inv; st0.y = o0[4*s+1] * inv;
        st0.z = o0[4*s+2] * inv; st0.w = o0[4*s+3] * inv;
        st1.x = o1[4*s+0] * inv; st1.y = o1[4*s+1] * inv;
        st1.z = o1[4*s+2] * inv; st1.w = o1[4*s+3] * inv;
        *(float4*)(op + 8 * s + 4 * h8)      = st0;
        *(float4*)(op + 32 + 8 * s + 4 * h8) = st1;
    }
}

extern "C" void kernel_launch(void* const* d_in, const int* in_sizes, int n_in,
                              void* d_out, int out_size, void* d_ws, size_t ws_size,
                              hipStream_t stream) {
    (void)in_sizes; (void)n_in; (void)out_size;
    const float* q = (const float*)d_in[0];
    const float* k = (const float*)d_in[1];
    const float* v = (const float*)d_in[2];
    const int*   m = (const int*)d_in[3];
    float* out = (float*)d_out;
    dim3 grid(NB * NH * (SS / QT));   // 512 blocks = 2 per CU

    if (ws_size >= WS_FULL) {
        u64t*   bits = (u64t*)d_ws;
        __bf16* kb16 = (__bf16*)((char*)d_ws + WS_KB_OFF);
        __bf16* vb16 = (__bf16*)((char*)d_ws + WS_VB_OFF);
        pre_kernel<<<dim3(6144), 256, 0, stream>>>(k, v, m, bits, kb16, vb16);
        attn2_kernel<<<grid, 256, 0, stream>>>(q, (const unsigned*)bits,
                                               kb16, vb16, out);
    } else if (ws_size >= WS_BITS_BYTES) {
        u64t* bits = (u64t*)d_ws;
        pack_mask_kernel<<<dim3(4096), 256, 0, stream>>>(m, bits);
        attn_kernel<1><<<grid, 512, 0, stream>>>(q, k, v, m, (const unsigned*)bits, out);
    } else {
        attn_kernel<0><<<grid, 512, 0, stream>>>(q, k, v, m, nullptr, out);
    }
}

// Round 7
// 270.065 us; speedup vs baseline: 1.2561x; 1.0048x over previous
//
#include <hip/hip_runtime.h>

#define NB 4
#define NH 16
#define SS 2048
#define DD 64
#define QT 256     // query rows per block
#define KT 64      // keys per tile (two 32-key halves)
#define NT (SS / KT)
#define KSP 72     // padded LDS row stride (bf16) -- measured conflict-free
#define QSCALE 0.18033688011112042f   // (1/8) * log2(e)  -> exp2 domain

#define WS_BITS_BYTES ((size_t)NB * SS * (SS / 8))   // 2 MiB
#define WS_KB_OFF  ((size_t)2  << 20)                // bf16 K (natural), 16 MiB
#define WS_VB_OFF  ((size_t)18 << 20)                // bf16 V^T(perm) tiles, 16 MiB
#define WS_FULL    ((size_t)34 << 20)

typedef __bf16 bf16x8 __attribute__((ext_vector_type(8)));
typedef __bf16 bf16x2 __attribute__((ext_vector_type(2)));
typedef float  floatx16 __attribute__((ext_vector_type(16)));
typedef unsigned long long u64t;

static_assert(sizeof(bf16x8) == 16, "bf16x8 must be 16B");

__device__ __forceinline__ int pack2(float a, float b) {
    bf16x2 v; v[0] = (__bf16)a; v[1] = (__bf16)b;
    return __builtin_bit_cast(int, v);
}

// permuted V column so QK C-regs feed PV B-fragment verbatim
__device__ __forceinline__ int vperm_col(int k) {
    return 16 * (k >> 4) + 8 * ((k >> 2) & 1) + (k & 3) + 4 * ((k >> 3) & 1);
}
__device__ __forceinline__ int vperm_inv(int c) {
    return 16 * ((c >> 4) & 3) + 8 * ((c >> 2) & 1) + 4 * ((c >> 3) & 1) + (c & 3);
}

// ---- fallback pre-pass: pack mask only ----
__global__ __launch_bounds__(256)
void pack_mask_kernel(const int* __restrict__ M, u64t* __restrict__ bits)
{
    const int w    = (blockIdx.x * 256 + threadIdx.x) >> 6;   // 0..16383
    const int lane = threadIdx.x & 63;
    #pragma unroll 4
    for (int i = 0; i < 16; ++i) {
        const int gw   = i * 16384 + w;
        const size_t row = (size_t)(gw >> 5);
        const int word = gw & 31;
        const int mval = M[row * SS + (size_t)word * 64 + lane];
        const u64t b = __ballot(mval == 1);
        if (lane == 0) bits[gw] = b;
    }
}

// ---- full pre-pass: K->bf16 (natural), V->bf16 transposed+permuted tiles,
// mask->bits.  blocks 0..2047: (bh,tt) K/V tiles.  2048..6143: mask pack. ----
__global__ __launch_bounds__(256)
void pre_kernel(const float* __restrict__ K, const float* __restrict__ V,
                const int* __restrict__ M, u64t* __restrict__ bits,
                __bf16* __restrict__ KB, __bf16* __restrict__ VB)
{
    __shared__ float vt[64][68];   // f32 V tile [key][dim], padded
    const int t = threadIdx.x;

    if (blockIdx.x < 2048) {
        const int bh = blockIdx.x >> 5;
        const int tt = blockIdx.x & 31;
        const size_t tb = (size_t)bh * SS * DD + (size_t)tt * (KT * DD);

        // K convert: pure elementwise, 16 elems/thread
        {
            const float* src = K + tb + t * 16;
            __bf16* dst = KB + tb + t * 16;
            float4 f0 = ((const float4*)src)[0];
            float4 f1 = ((const float4*)src)[1];
            float4 f2 = ((const float4*)src)[2];
            float4 f3 = ((const float4*)src)[3];
            bf16x8 o0, o1;
            o0[0]=(__bf16)f0.x; o0[1]=(__bf16)f0.y; o0[2]=(__bf16)f0.z; o0[3]=(__bf16)f0.w;
            o0[4]=(__bf16)f1.x; o0[5]=(__bf16)f1.y; o0[6]=(__bf16)f1.z; o0[7]=(__bf16)f1.w;
            o1[0]=(__bf16)f2.x; o1[1]=(__bf16)f2.y; o1[2]=(__bf16)f2.z; o1[3]=(__bf16)f2.w;
            o1[4]=(__bf16)f3.x; o1[5]=(__bf16)f3.y; o1[6]=(__bf16)f3.z; o1[7]=(__bf16)f3.w;
            ((bf16x8*)dst)[0] = o0;
            ((bf16x8*)dst)[1] = o1;
        }

        // V tile -> LDS (f32), then transposed+permuted bf16 out [dim][64]
        {
            const int key = t >> 2, ds = (t & 3) * 16;
            const float* src = V + tb + (size_t)key * DD + ds;
            #pragma unroll
            for (int i = 0; i < 4; ++i)
                *(float4*)&vt[key][ds + 4 * i] = ((const float4*)src)[i];
        }
        __syncthreads();
        {
            const int dim = t >> 2, cb = (t & 3) * 16;
            bf16x8 o0, o1;
            #pragma unroll
            for (int c = 0; c < 16; ++c) {
                const float vvv = vt[vperm_inv(cb + c)][dim];
                if (c < 8) o0[c] = (__bf16)vvv; else o1[c - 8] = (__bf16)vvv;
            }
            __bf16* dst = VB + tb + (size_t)dim * 64 + cb;
            ((bf16x8*)dst)[0] = o0;
            ((bf16x8*)dst)[1] = o1;
        }
    } else {
        const int w    = ((blockIdx.x - 2048) * 256 + t) >> 6;   // 0..16383
        const int lane = t & 63;
        #pragma unroll 4
        for (int i = 0; i < 16; ++i) {
            const int gw   = i * 16384 + w;
            const size_t row = (size_t)(gw >> 5);
            const int word = gw & 31;
            const int mval = M[row * SS + (size_t)word * 64 + lane];
            const u64t b = __ballot(mval == 1);
            if (lane == 0) bits[gw] = b;
        }
    }
}

// ===================== fast path: 4 waves, 64 q-rows per wave ================
// Tile body restructured for pipe overlap: all 16 QK MFMAs issue as one
// stream; softmax(h1) sits between PV(h0) and PV(h1) so its exp2/pack
// issue in the shadow of PV MFMAs.  Denominator via float psums (no oL).
__global__ __launch_bounds__(256, 2)
void attn2_kernel(const float* __restrict__ Q, const unsigned* __restrict__ MBu,
                  const __bf16* __restrict__ KB, const __bf16* __restrict__ VB,
                  float* __restrict__ O)
{
    __shared__ __bf16 ks [2][KT][KSP];   // [buf][key][dim]
    __shared__ __bf16 vsT[2][DD][KSP];   // [buf][dim][perm-key]

    const int t    = threadIdx.x;
    const int lane = t & 63;
    const int l31  = lane & 31;
    const int h8   = lane >> 5;
    const int wave = t >> 6;

    // XCD-affinity decode: all 8 q-tiles of a head share blockIdx%8 -> one XCD L2
    const int bh    = blockIdx.x & 63;
    const int qtile = blockIdx.x >> 6;          // 0..7
    const int b     = bh >> 4;
    const int q0    = qtile * QT + wave * 64;   // 64 q-rows per wave

    const size_t base = (size_t)bh * SS * DD;

    // ---- persistent Q B-fragments for the two 32-q groups ----
    bf16x8 aqA[4], aqB[4];
    #pragma unroll
    for (int grp = 0; grp < 2; ++grp) {
        const float* qp = Q + base + (size_t)(q0 + 32 * grp + l31) * DD + 8 * h8;
        #pragma unroll
        for (int s = 0; s < 4; ++s) {
            float4 f0 = *(const float4*)(qp + 16 * s);
            float4 f1 = *(const float4*)(qp + 16 * s + 4);
            bf16x8 a;
            a[0] = (__bf16)(f0.x * QSCALE); a[1] = (__bf16)(f0.y * QSCALE);
            a[2] = (__bf16)(f0.z * QSCALE); a[3] = (__bf16)(f0.w * QSCALE);
            a[4] = (__bf16)(f1.x * QSCALE); a[5] = (__bf16)(f1.y * QSCALE);
            a[6] = (__bf16)(f1.z * QSCALE); a[7] = (__bf16)(f1.w * QSCALE);
            if (grp == 0) aqA[s] = a; else aqB[s] = a;
        }
    }

    // ---- staging: thread stages rows srow and srow+32 of K and of V^T ----
    const int srow = t >> 3;            // 0..31
    const int sc8  = (t & 7) * 8;
    const __bf16* kbp = KB + base + (size_t)srow * DD + sc8;
    const __bf16* vbp = VB + base + (size_t)srow * DD + sc8;
    bf16x8 kr0, kr1, vr0, vr1;

    kr0 = *(const bf16x8*)kbp;
    kr1 = *(const bf16x8*)(kbp + 32 * DD);
    vr0 = *(const bf16x8*)vbp;
    vr1 = *(const bf16x8*)(vbp + 32 * DD);

    // mask rows for the two q groups, prefetched one tile ahead
    const u64t* mbrA = (const u64t*)MBu + ((size_t)b * SS + q0 + l31)      * (SS / 64);
    const u64t* mbrB = (const u64t*)MBu + ((size_t)b * SS + q0 + 32 + l31) * (SS / 64);
    u64t mA = mbrA[0], mB = mbrB[0], mnA, mnB;

    floatx16 o0A, o1A, o0B, o1B;
    #pragma unroll
    for (int i = 0; i < 16; ++i) {
        o0A[i] = 0.f; o1A[i] = 0.f; o0B[i] = 0.f; o1B[i] = 0.f;
    }
    float lsA = 0.f, lsB = 0.f;

    for (int tt = 0; tt < NT; ++tt) {
        const int cur = tt & 1;

        // ---- stage K/V tile tt -> LDS buf[cur] ----
        *(bf16x8*)&ks [cur][srow]     [sc8] = kr0;
        *(bf16x8*)&ks [cur][srow + 32][sc8] = kr1;
        *(bf16x8*)&vsT[cur][srow]     [sc8] = vr0;
        *(bf16x8*)&vsT[cur][srow + 32][sc8] = vr1;

        // barrier draining LDS only; VMEM prefetches stay in flight
        asm volatile("s_waitcnt lgkmcnt(0)" ::: "memory");
        __builtin_amdgcn_s_barrier();
        asm volatile("" ::: "memory");

        // ---- prefetch next tile + next mask words ----
        {
            const size_t jn = (size_t)((tt + 1) & (NT - 1)) * (KT * DD);
            kr0 = *(const bf16x8*)(kbp + jn);
            kr1 = *(const bf16x8*)(kbp + jn + 32 * DD);
            vr0 = *(const bf16x8*)(vbp + jn);
            vr1 = *(const bf16x8*)(vbp + jn + 32 * DD);
        }
        mnA = mbrA[(tt + 1) & (NT - 1)];
        mnB = mbrB[(tt + 1) & (NT - 1)];

        __builtin_amdgcn_s_setprio(1);

        // ---- K fragments for BOTH halves (one lgkm wait, no mid-stream stalls)
        bf16x8 kf0[4], kf1[4];
        #pragma unroll
        for (int s = 0; s < 4; ++s) {
            kf0[s] = *(const bf16x8*)&ks[cur][l31]     [16 * s + 8 * h8];
            kf1[s] = *(const bf16x8*)&ks[cur][32 + l31][16 * s + 8 * h8];
        }

        // ---- mask-as-C-init for both halves/groups ----
        floatx16 cA0, cB0, cA1, cB1;
        {
            const unsigned uA0 = (unsigned)(mA)       >> (4 * h8);
            const unsigned uB0 = (unsigned)(mB)       >> (4 * h8);
            const unsigned uA1 = (unsigned)(mA >> 32) >> (4 * h8);
            const unsigned uB1 = (unsigned)(mB >> 32) >> (4 * h8);
            #pragma unroll
            for (int i = 0; i < 16; ++i) {
                const int pos = (i & 3) + 8 * (i >> 2);
                cA0[i] = __builtin_bit_cast(float, (((int)(uA0 << (31 - pos))) >> 31) & (int)0xC4800000u);
                cB0[i] = __builtin_bit_cast(float, (((int)(uB0 << (31 - pos))) >> 31) & (int)0xC4800000u);
                cA1[i] = __builtin_bit_cast(float, (((int)(uA1 << (31 - pos))) >> 31) & (int)0xC4800000u);
                cB1[i] = __builtin_bit_cast(float, (((int)(uB1 << (31 - pos))) >> 31) & (int)0xC4800000u);
            }
        }

        // ---- QK: 16 MFMA as one stream (4 independent accumulator chains) ----
        #pragma unroll
        for (int s = 0; s < 4; ++s) {
            cA0 = __builtin_amdgcn_mfma_f32_32x32x16_bf16(kf0[s], aqA[s], cA0, 0, 0, 0);
            cB0 = __builtin_amdgcn_mfma_f32_32x32x16_bf16(kf0[s], aqB[s], cB0, 0, 0, 0);
            cA1 = __builtin_amdgcn_mfma_f32_32x32x16_bf16(kf1[s], aqA[s], cA1, 0, 0, 0);
            cB1 = __builtin_amdgcn_mfma_f32_32x32x16_bf16(kf1[s], aqB[s], cB1, 0, 0, 0);
        }

        // ---- softmax h0 (runs while QK tail executes) ----
        int pkA0[8], pkB0[8];
        {
            float sa0 = 0.f, sa1 = 0.f, sb0 = 0.f, sb1 = 0.f;
            #pragma unroll
            for (int g = 0; g < 8; ++g) {
                float a0 = __builtin_amdgcn_exp2f(cA0[2 * g]);
                float a1 = __builtin_amdgcn_exp2f(cA0[2 * g + 1]);
                float b0 = __builtin_amdgcn_exp2f(cB0[2 * g]);
                float b1 = __builtin_amdgcn_exp2f(cB0[2 * g + 1]);
                sa0 += a0; sa1 += a1; sb0 += b0; sb1 += b1;
                pkA0[g] = pack2(a0, a1);
                pkB0[g] = pack2(b0, b1);
            }
            lsA += sa0 + sa1; lsB += sb0 + sb1;
        }

        // ---- PV h0 (V frags read here; sm h1 below issues in MFMA shadow) ----
        #pragma unroll
        for (int s2 = 0; s2 < 2; ++s2) {
            bf16x8 av0 = *(const bf16x8*)&vsT[cur][l31]     [16 * s2 + 8 * h8];
            bf16x8 av1 = *(const bf16x8*)&vsT[cur][32 + l31][16 * s2 + 8 * h8];
            int4 fwA; fwA.x = pkA0[4*s2]; fwA.y = pkA0[4*s2+1]; fwA.z = pkA0[4*s2+2]; fwA.w = pkA0[4*s2+3];
            int4 fwB; fwB.x = pkB0[4*s2]; fwB.y = pkB0[4*s2+1]; fwB.z = pkB0[4*s2+2]; fwB.w = pkB0[4*s2+3];
            bf16x8 bpA = __builtin_bit_cast(bf16x8, fwA);
            bf16x8 bpB = __builtin_bit_cast(bf16x8, fwB);
            o0A = __builtin_amdgcn_mfma_f32_32x32x16_bf16(av0, bpA, o0A, 0, 0, 0);
            o0B = __builtin_amdgcn_mfma_f32_32x32x16_bf16(av0, bpB, o0B, 0, 0, 0);
            o1A = __builtin_amdgcn_mfma_f32_32x32x16_bf16(av1, bpA, o1A, 0, 0, 0);
            o1B = __builtin_amdgcn_mfma_f32_32x32x16_bf16(av1, bpB, o1B, 0, 0, 0);
        }

        // ---- softmax h1 ----
        int pkA1[8], pkB1[8];
        {
            float sa0 = 0.f, sa1 = 0.f, sb0 = 0.f, sb1 = 0.f;
            #pragma unroll
            for (int g = 0; g < 8; ++g) {
                float a0 = __builtin_amdgcn_exp2f(cA1[2 * g]);
                float a1 = __builtin_amdgcn_exp2f(cA1[2 * g + 1]);
                float b0 = __builtin_amdgcn_exp2f(cB1[2 * g]);
                float b1 = __builtin_amdgcn_exp2f(cB1[2 * g + 1]);
                sa0 += a0; sa1 += a1; sb0 += b0; sb1 += b1;
                pkA1[g] = pack2(a0, a1);
                pkB1[g] = pack2(b0, b1);
            }
            lsA += sa0 + sa1; lsB += sb0 + sb1;
        }

        // ---- PV h1 ----
        #pragma unroll
        for (int s2 = 0; s2 < 2; ++s2) {
            bf16x8 av0 = *(const bf16x8*)&vsT[cur][l31]     [32 + 16 * s2 + 8 * h8];
            bf16x8 av1 = *(const bf16x8*)&vsT[cur][32 + l31][32 + 16 * s2 + 8 * h8];
            int4 fwA; fwA.x = pkA1[4*s2]; fwA.y = pkA1[4*s2+1]; fwA.z = pkA1[4*s2+2]; fwA.w = pkA1[4*s2+3];
            int4 fwB; fwB.x = pkB1[4*s2]; fwB.y = pkB1[4*s2+1]; fwB.z = pkB1[4*s2+2]; fwB.w = pkB1[4*s2+3];
            bf16x8 bpA = __builtin_bit_cast(bf16x8, fwA);
            bf16x8 bpB = __builtin_bit_cast(bf16x8, fwB);
            o0A = __builtin_amdgcn_mfma_f32_32x32x16_bf16(av0, bpA, o0A, 0, 0, 0);
            o0B = __builtin_amdgcn_mfma_f32_32x32x16_bf16(av0, bpB, o0B, 0, 0, 0);
            o1A = __builtin_amdgcn_mfma_f32_32x32x16_bf16(av1, bpA, o1A, 0, 0, 0);
            o1B = __builtin_amdgcn_mfma_f32_32x32x16_bf16(av1, bpB, o1B, 0, 0, 0);
        }

        __builtin_amdgcn_s_setprio(0);

        mA = mnA; mB = mnB;
    }

    // ---- epilogue: denominator = own half-sum + partner half (h8 pair) ----
    lsA += __shfl_xor(lsA, 32);
    lsB += __shfl_xor(lsB, 32);
    const float invA = 1.0f / lsA;
    const float invB = 1.0f / lsB;
    float* opA = O + base + (size_t)(q0 + l31) * DD;
    float* opB = O + base + (size_t)(q0 + 32 + l31) * DD;
    #pragma unroll
    for (int s = 0; s < 4; ++s) {
        float4 st;
        st.x = o0A[4*s+0] * invA; st.y = o0A[4*s+1] * invA;
        st.z = o0A[4*s+2] * invA; st.w = o0A[4*s+3] * invA;
        *(float4*)(opA + 8 * s + 4 * h8) = st;
        st.x = o1A[4*s+0] * invA; st.y = o1A[4*s+1] * invA;
        st.z = o1A[4*s+2] * invA; st.w = o1A[4*s+3] * invA;
        *(float4*)(opA + 32 + 8 * s + 4 * h8) = st;
        st.x = o0B[4*s+0] * invB; st.y = o0B[4*s+1] * invB;
        st.z = o0B[4*s+2] * invB; st.w = o0B[4*s+3] * invB;
        *(float4*)(opB + 8 * s + 4 * h8) = st;
        st.x = o1B[4*s+0] * invB; st.y = o1B[4*s+1] * invB;
        st.z = o1B[4*s+2] * invB; st.w = o1B[4*s+3] * invB;
        *(float4*)(opB + 32 + 8 * s + 4 * h8) = st;
    }
}

// ===================== fallback path (R4-verified): 8 waves, 32 q per wave ===
// MODE 1: f32 staging + bit-mask.  MODE 0: f32 staging + raw int mask.
template<int MODE>
__global__ __launch_bounds__(512, 4)
void attn_kernel(const float* __restrict__ Q, const float* __restrict__ K,
                 const float* __restrict__ V, const int* __restrict__ M,
                 const unsigned* __restrict__ MB, float* __restrict__ O)
{
    __shared__ __bf16 ks [2][KT][KSP];
    __shared__ __bf16 vsT[2][DD][KSP];

    const int t    = threadIdx.x;
    const int wave = t >> 6;
    const int lane = t & 63;
    const int l31  = lane & 31;
    const int h8   = lane >> 5;

    const int bh    = blockIdx.x & 63;
    const int qtile = blockIdx.x >> 6;
    const int b     = bh >> 4;
    const int q0    = qtile * QT + wave * 32;

    const size_t base = (size_t)bh * SS * DD;

    bf16x8 aq[4];
    {
        const float* qp = Q + base + (size_t)(q0 + l31) * DD + 8 * h8;
        #pragma unroll
        for (int s = 0; s < 4; ++s) {
            float4 f0 = *(const float4*)(qp + 16 * s);
            float4 f1 = *(const float4*)(qp + 16 * s + 4);
            bf16x8 a;
            a[0] = (__bf16)(f0.x * QSCALE); a[1] = (__bf16)(f0.y * QSCALE);
            a[2] = (__bf16)(f0.z * QSCALE); a[3] = (__bf16)(f0.w * QSCALE);
            a[4] = (__bf16)(f1.x * QSCALE); a[5] = (__bf16)(f1.y * QSCALE);
            a[6] = (__bf16)(f1.z * QSCALE); a[7] = (__bf16)(f1.w * QSCALE);
            aq[s] = a;
        }
    }

    bf16x8 ones8;
    #pragma unroll
    for (int i = 0; i < 8; ++i) ones8[i] = (__bf16)1.0f;

    const int skey = t >> 3;
    const int sdc  = (t & 7) * 8;
    const int vk   = 2 * (t & 31);
    const int vdc  = (t >> 5) * 4;
    const int vcol = vperm_col(vk);
    const float* kp0 = K + base + (size_t)skey * DD + sdc;
    const float* vp0 = V + base + (size_t)vk * DD + vdc;

    float4 ka0 = ((const float4*)kp0)[0];
    float4 ka1 = ((const float4*)kp0)[1];
    float4 va0 = *(const float4*)(vp0);
    float4 va1 = *(const float4*)(vp0 + DD);

    const u64t* mbrow = (const u64t*)MB + ((size_t)b * SS + q0 + l31) * (SS / 64);
    const int*  mrow  = M + (size_t)b * SS * SS + (size_t)(q0 + l31) * SS + 4 * h8;
    u64t mall = 0, mnext = 0;
    if constexpr (MODE >= 1) mall = mbrow[0];

    floatx16 o0, o1, oL;
    #pragma unroll
    for (int i = 0; i < 16; ++i) { o0[i] = 0.f; o1[i] = 0.f; oL[i] = 0.f; }

    for (int tt = 0; tt < NT; ++tt) {
        const int cur = tt & 1;

        {
            bf16x8 kw;
            kw[0]=(__bf16)ka0.x; kw[1]=(__bf16)ka0.y; kw[2]=(__bf16)ka0.z; kw[3]=(__bf16)ka0.w;
            kw[4]=(__bf16)ka1.x; kw[5]=(__bf16)ka1.y; kw[6]=(__bf16)ka1.z; kw[7]=(__bf16)ka1.w;
            *(bf16x8*)&ks[cur][skey][sdc] = kw;
            #pragma unroll
            for (int i = 0; i < 4; ++i) {
                bf16x2 pr;
                pr[0] = (__bf16)(&va0.x)[i]; pr[1] = (__bf16)(&va1.x)[i];
                *(bf16x2*)&vsT[cur][vdc + i][vcol] = pr;
            }
        }
        __syncthreads();

        int4 mi[8];
        if constexpr (MODE == 0) {
            #pragma unroll
            for (int g = 0; g < 8; ++g)
                mi[g] = *(const int4*)(mrow + tt * KT + 8 * g);
        }

        {
            const int jn = ((tt + 1) * KT) & (SS - 1);
            const float* kn = kp0 + (size_t)jn * DD;
            ka0 = ((const float4*)kn)[0];
            ka1 = ((const float4*)kn)[1];
            const float* vn = vp0 + (size_t)jn * DD;
            va0 = *(const float4*)(vn);
            va1 = *(const float4*)(vn + DD);
        }
        if constexpr (MODE >= 1) mnext = mbrow[(tt + 1) & (NT - 1)];

        #pragma unroll
        for (int half = 0; half < 2; ++half) {
            floatx16 c;
            if constexpr (MODE >= 1) {
                const unsigned u = (unsigned)(mall >> (32 * half)) >> (4 * h8);
                #pragma unroll
                for (int i = 0; i < 16; ++i) {
                    const int pos = (i & 3) + 8 * (i >> 2);
                    const int sm = ((int)(u << (31 - pos))) >> 31;
                    c[i] = __builtin_bit_cast(float, sm & (int)0xC4800000u);
                }
            } else {
                #pragma unroll
                for (int i = 0; i < 16; ++i) {
                    const int g2 = 4 * half + (i >> 2);
                    c[i] = ((&mi[g2].x)[i & 3] == 1) ? -1024.0f : 0.0f;
                }
            }

            __builtin_amdgcn_s_setprio(1);
            #pragma unroll
            for (int s = 0; s < 4; ++s) {
                bf16x8 a = *(const bf16x8*)&ks[cur][32 * half + l31][16 * s + 8 * h8];
                c = __builtin_amdgcn_mfma_f32_32x32x16_bf16(a, aq[s], c, 0, 0, 0);
            }
            __builtin_amdgcn_s_setprio(0);

            int pk[8];
            #pragma unroll
            for (int g = 0; g < 8; ++g) {
                float pa = __builtin_amdgcn_exp2f(c[2 * g]);
                float pb = __builtin_amdgcn_exp2f(c[2 * g + 1]);
                pk[g] = pack2(pa, pb);
            }

            __builtin_amdgcn_s_setprio(1);
            #pragma unroll
            for (int s2 = 0; s2 < 2; ++s2) {
                int4 fw; fw.x = pk[4*s2]; fw.y = pk[4*s2+1]; fw.z = pk[4*s2+2]; fw.w = pk[4*s2+3];
                bf16x8 bp = __builtin_bit_cast(bf16x8, fw);
                bf16x8 av0 = *(const bf16x8*)&vsT[cur][l31]     [32 * half + 16 * s2 + 8 * h8];
                bf16x8 av1 = *(const bf16x8*)&vsT[cur][32 + l31][32 * half + 16 * s2 + 8 * h8];
                o0 = __builtin_amdgcn_mfma_f32_32x32x16_bf16(av0, bp, o0, 0, 0, 0);
                o1 = __builtin_amdgcn_mfma_f32_32x32x16_bf16(av1, bp, o1, 0, 0, 0);
                oL = __builtin_amdgcn_mfma_f32_32x32x16_bf16(ones8, bp, oL, 0, 0, 0);
            }
            __builtin_amdgcn_s_setprio(0);
        }

        if constexpr (MODE >= 1) mall = mnext;
    }

    float inv = 1.0f / oL[0];
    float* op = O + base + (size_t)(q0 + l31) * DD;
    #pragma unroll
    for (int s = 0; s < 4; ++s) {
        float4 st0, st1;
        st0.x = o0[4*s+0] * inv; st0.y = o0[4*s+1] * inv;
        st0.z = o0[4*s+2] * inv; st0.w = o0[4*s+3] * inv;
        st1.x = o1[4*s+0] * inv; st1.y = o1[4*s+1] * inv;
        st1.z = o1[4*s+2] * inv; st1.w = o1[4*s+3] * inv;
        *(float4*)(op + 8 * s + 4 * h8)      = st0;
        *(float4*)(op + 32 + 8 * s + 4 * h8) = st1;
    }
}

extern "C" void kernel_launch(void* const* d_in, const int* in_sizes, int n_in,
                              void* d_out, int out_size, void* d_ws, size_t ws_size,
                              hipStream_t stream) {
    (void)in_sizes; (void)n_in; (void)out_size;
    const float* q = (const float*)d_in[0];
    const float* k = (const float*)d_in[1];
    const float* v = (const float*)d_in[2];
    const int*   m = (const int*)d_in[3];
    float* out = (float*)d_out;
    dim3 grid(NB * NH * (SS / QT));   // 512 blocks = 2 per CU

    if (ws_size >= WS_FULL) {
        u64t*   bits = (u64t*)d_ws;
        __bf16* kb16 = (__bf16*)((char*)d_ws + WS_KB_OFF);
        __bf16* vb16 = (__bf16*)((char*)d_ws + WS_VB_OFF);
        pre_kernel<<<dim3(6144), 256, 0, stream>>>(k, v, m, bits, kb16, vb16);
        attn2_kernel<<<grid, 256, 0, stream>>>(q, (const unsigned*)bits,
                                               kb16, vb16, out);
    } else if (ws_size >= WS_BITS_BYTES) {
        u64t* bits = (u64t*)d_ws;
        pack_mask_kernel<<<dim3(4096), 256, 0, stream>>>(m, bits);
        attn_kernel<1><<<grid, 512, 0, stream>>>(q, k, v, m, (const unsigned*)bits, out);
    } else {
        attn_kernel<0><<<grid, 512, 0, stream>>>(q, k, v, m, nullptr, out);
    }
}